// Round 5
// baseline (179.174 us; speedup 1.0000x reference)
//
#include <hip/hip_runtime.h>

// y[n,f] = sum_p w_table[widx[n],p] * pool[idx[n,p],f]
// pool = concat(values0, values1). N=500000, P=16, F=32, M=200000, K=10000.
// 8 lanes per neuron-fragment, one float4 per lane (full 128B row per 8-lane
// group, perfectly coalesced). Round 5: persistent grid-stride kernel —
// 2048 long-lived blocks instead of 15625 short-lived ones. Removes workgroup
// dispatch churn (occupancy was stuck at 65%) and lets the loop pipeline the
// next iteration's idx/w loads under the current iteration's gathers/FMAs.
// Round-4 lesson: do NOT force per-wave MLP (asm batch barrier) — TLP loss
// costs more than ILP gains.

#define PP 16
#define FF 32

typedef float f32x4 __attribute__((ext_vector_type(4)));

__global__ __launch_bounds__(256, 8) void linear_gather_kernel(
    const float* __restrict__ values0,
    const float* __restrict__ values1,
    const float* __restrict__ w_table,
    const int*   __restrict__ idx,
    const int*   __restrict__ widx,
    float*       __restrict__ out,
    int N, int M)
{
    const long total  = (long)N * 8;
    const long stride = (long)gridDim.x * blockDim.x;

    for (long t = (long)blockIdx.x * blockDim.x + threadIdx.x;
         t < total; t += stride)
    {
        int n  = (int)(t >> 3);   // neuron
        int f4 = (int)(t & 7);    // which float4 of the 32-float row

        const int*   irow = idx + (long)n * PP;
        const float* wrow = w_table + (long)widx[n] * PP;

        f32x4 acc = (f32x4)(0.f);
#pragma unroll
        for (int p = 0; p < PP; ++p) {
            int   i = irow[p];     // same addr across the 8 lanes -> broadcast
            float w = wrow[p];     // same addr across the 8 lanes -> broadcast
            const float* src = (i < M) ? (values0 + (long)i * FF)
                                       : (values1 + (long)(i - M) * FF);
            f32x4 v = *reinterpret_cast<const f32x4*>(src + f4 * 4);
            acc.x = fmaf(w, v.x, acc.x);
            acc.y = fmaf(w, v.y, acc.y);
            acc.z = fmaf(w, v.z, acc.z);
            acc.w = fmaf(w, v.w, acc.w);
        }

        // Streamed output — nontemporal store, don't evict pool rows from L2.
        __builtin_nontemporal_store(acc, reinterpret_cast<f32x4*>(out) + t);
    }
}

extern "C" void kernel_launch(void* const* d_in, const int* in_sizes, int n_in,
                              void* d_out, int out_size, void* d_ws, size_t ws_size,
                              hipStream_t stream) {
    const float* values0 = (const float*)d_in[0];
    const float* values1 = (const float*)d_in[1];
    const float* w_table = (const float*)d_in[2];
    const int*   idx     = (const int*)d_in[3];
    const int*   widx    = (const int*)d_in[4];
    float*       out     = (float*)d_out;

    const int N = in_sizes[4];          // widx has N elements
    const int M = in_sizes[0] / FF;     // values0 rows

    // Persistent: 8 blocks/CU x 256 CUs.
    int block = 256;
    int grid  = 2048;

    linear_gather_kernel<<<grid, block, 0, stream>>>(
        values0, values1, w_table, idx, widx, out, N, M);
}